// Round 2
// baseline (117.884 us; speedup 1.0000x reference)
//
#include <hip/hip_runtime.h>
#include <stdint.h>

#define NB 128
#define G 32
#define G2 1024
#define NC 80
#define ST 90            // 80 logits + 2*5 bbox
#define IMGW 448.0f
#define NCELL (NB * G2)

// ---------------------------------------------------------------------------
// Kernel 1: decode, 16 lanes per cell (256 threads = 16 cells per block).
// Each lane reads float2 slots {l, l+16, l+32} of the 45-float2 row ->
// every wave-load covers 4 contiguous 128B chunks. Argmax over 80 logits by
// 16-lane shuffle reduce. Small outputs staged via LDS for coalesced stores.
// ---------------------------------------------------------------------------
__global__ __launch_bounds__(256) void percell_kernel(
    const float* __restrict__ x,
    float* __restrict__ out0, float* __restrict__ out1,
    float* __restrict__ out2, float* __restrict__ out3,
    float* __restrict__ out4, int* __restrict__ ws_label)
{
#pragma clang fp contract(off)
    __shared__ float s_out1[16 * 5];
    __shared__ float4 s_out2[16];
    __shared__ float s_out3[16];
    __shared__ float s_out4[16];
    __shared__ int   s_lab[16];

    const int t = threadIdx.x;
    const int lane = t & 15;          // lane within 16-group
    const int grp  = t >> 4;          // 0..15, cell within block
    const int l64  = t & 63;
    const int base = l64 & 48;        // group base within the 64-wave
    const int cell = blockIdx.x * 16 + grp;

    const float2* p2 = (const float2*)x + (size_t)cell * 45;
    float2* o0 = (float2*)out0 + (size_t)cell * 40;

    float bv = -INFINITY;
    int bi = 0;

    // round 1: slots 0-15 (logits 0-31)
    float2 a = p2[lane];
    o0[lane] = a;
    if (a.x > bv) { bv = a.x; bi = 2 * lane; }
    if (a.y > bv) { bv = a.y; bi = 2 * lane + 1; }
    // round 2: slots 16-31 (logits 32-63)
    float2 bq = p2[lane + 16];
    o0[lane + 16] = bq;
    if (bq.x > bv) { bv = bq.x; bi = 32 + 2 * lane; }
    if (bq.y > bv) { bv = bq.y; bi = 32 + 2 * lane + 1; }
    // round 3: slots 32-44 (logits 64-79 on lanes 0-7; bbox on lanes 8-12)
    float2 cq = make_float2(0.0f, 0.0f);
    if (lane < 13) cq = p2[lane + 32];
    if (lane < 8) {
        o0[lane + 32] = cq;
        if (cq.x > bv) { bv = cq.x; bi = 64 + 2 * lane; }
        if (cq.y > bv) { bv = cq.y; bi = 64 + 2 * lane + 1; }
    }

    // 16-lane argmax reduce (ties -> smaller index)
#pragma unroll
    for (int o = 1; o < 16; o <<= 1) {
        float ov = __shfl_xor(bv, o, 64);
        int   oi = __shfl_xor(bi, o, 64);
        if (ov > bv || (ov == bv && oi < bi)) { bv = ov; bi = oi; }
    }

    // gather bbox float2s (slots 40-44 live on lanes base+8..base+12)
    float f40x = __shfl(cq.x, base + 8, 64),  f40y = __shfl(cq.y, base + 8, 64);
    float f41x = __shfl(cq.x, base + 9, 64),  f41y = __shfl(cq.y, base + 9, 64);
    float f42x = __shfl(cq.x, base + 10, 64), f42y = __shfl(cq.y, base + 10, 64);
    float f43x = __shfl(cq.x, base + 11, 64), f43y = __shfl(cq.y, base + 11, 64);
    float f44x = __shfl(cq.x, base + 12, 64), f44y = __shfl(cq.y, base + 12, 64);

    if (lane == 0) {
        float b0, b1, b2, b3, b4;
        if (f44y > f42x) { b0 = f42y; b1 = f43x; b2 = f43y; b3 = f44x; b4 = f44y; }
        else             { b0 = f40x; b1 = f40y; b2 = f41x; b3 = f41y; b4 = f42x; }

        s_out1[grp * 5 + 0] = b0; s_out1[grp * 5 + 1] = b1;
        s_out1[grp * 5 + 2] = b2; s_out1[grp * 5 + 3] = b3;
        s_out1[grp * 5 + 4] = b4;

        int g = cell & (G2 - 1);
        float xg = (float)(g & (G - 1));
        float yg = (float)(g >> 5);
        float cx = (b0 + xg) / 32.0f;
        float cy = (b1 + yg) / 32.0f;
        float hw = b2 / 2.0f, hh = b3 / 2.0f;
        float x0 = fminf(fmaxf((cx - hw) * IMGW, 0.0f), IMGW);
        float y0 = fminf(fmaxf((cy - hh) * IMGW, 0.0f), IMGW);
        float x1 = fminf(fmaxf((cx + hw) * IMGW, 0.0f), IMGW);
        float y1 = fminf(fmaxf((cy + hh) * IMGW, 0.0f), IMGW);

        s_out2[grp] = make_float4(x0, y0, x1, y1);
        s_out3[grp] = b4;
        s_out4[grp] = (b4 > 0.1f) ? 1.0f : 0.0f;
        s_lab[grp] = bi;
    }
    __syncthreads();

    // coalesced stores from LDS (disjoint thread windows)
    if (t < 80)                 out1[(size_t)blockIdx.x * 80 + t] = s_out1[t];
    else if (t >= 80 && t < 96) out3[(size_t)blockIdx.x * 16 + (t - 80)] = s_out3[t - 80];
    else if (t < 112)           out4[(size_t)blockIdx.x * 16 + (t - 96)] = s_out4[t - 96];
    else if (t < 128)           ws_label[(size_t)blockIdx.x * 16 + (t - 112)] = s_lab[t - 112];
    else if (t < 144)           ((float4*)out2)[(size_t)blockIdx.x * 16 + (t - 128)] = s_out2[t - 128];
}

// ---------------------------------------------------------------------------
// Kernel 2: per-image NMS, 256 threads/block, one block per image.
// Counting-sort by class (histogram + prefix + cursor scatter), ~13-element
// insertion sort per class segment on 64-bit (score-desc | idx-asc) keys,
// then per-class serial greedy NMS. Cross-class IoU is exactly 0 (class
// offsets >= 1.0 apart), so this equals the reference's global greedy NMS.
// ---------------------------------------------------------------------------
__global__ __launch_bounds__(256) void nms_kernel(
    const float4* __restrict__ boxes, const float* __restrict__ scores,
    const int* __restrict__ labels, float* __restrict__ out5)
{
#pragma clang fp contract(off)
    __shared__ float4 obox_s[G2];                 // by orig idx, 16 KB
    __shared__ float  area_s[G2];                 // 4 KB
    __shared__ unsigned long long seg[G2];        // class-segmented keys, 8 KB
    __shared__ int cnt_s[NC];
    __shared__ int start_s[NC];
    __shared__ int cur_s[NC];
    __shared__ unsigned char keep_s[G2];
    __shared__ float redbuf[4];

    const int n = blockIdx.x;
    const int t = threadIdx.x;

    float4 b[4]; float sc[4]; int lab[4]; bool res[4];
    float m = 0.0f;
#pragma unroll
    for (int k = 0; k < 4; ++k) {
        int i = t + k * 256;
        int cell = n * G2 + i;
        b[k] = boxes[cell];
        sc[k] = scores[cell];
        lab[k] = labels[cell];
        res[k] = sc[k] > 0.1f;
        if (res[k]) m = fmaxf(m, fmaxf(fmaxf(b[k].x, b[k].y), fmaxf(b[k].z, b[k].w)));
        keep_s[i] = 0;
    }
    if (t < NC) { cnt_s[t] = 0; cur_s[t] = 0; }
#pragma unroll
    for (int o = 32; o > 0; o >>= 1) m = fmaxf(m, __shfl_xor(m, o, 64));
    if ((t & 63) == 0) redbuf[t >> 6] = m;
    __syncthreads();
    if (t == 0)
        redbuf[0] = fmaxf(fmaxf(redbuf[0], redbuf[1]), fmaxf(redbuf[2], redbuf[3]));
    __syncthreads();
    const float mult = redbuf[0] + 1.0f;

    // obox + area + class histogram
#pragma unroll
    for (int k = 0; k < 4; ++k) {
        int i = t + k * 256;
        float off = (float)lab[k] * mult;          // one rounding (no fma)
        float4 ob = make_float4(b[k].x + off, b[k].y + off, b[k].z + off, b[k].w + off);
        obox_s[i] = ob;
        area_s[i] = fmaxf(ob.z - ob.x, 0.0f) * fmaxf(ob.w - ob.y, 0.0f);
        if (res[k]) atomicAdd(&cnt_s[lab[k]], 1);
    }
    __syncthreads();

    // exclusive prefix over 80 class counts
    if (t < NC) {
        int s = 0;
        for (int c = 0; c < t; ++c) s += cnt_s[c];
        start_s[t] = s;
    }
    __syncthreads();

    // scatter keys into class segments
#pragma unroll
    for (int k = 0; k < 4; ++k) {
        int i = t + k * 256;
        if (res[k]) {
            unsigned d = ~__float_as_uint(sc[k]);  // positive floats: descending
            int slot = atomicAdd(&cur_s[lab[k]], 1);
            seg[start_s[lab[k]] + slot] = ((unsigned long long)d << 10) | (unsigned)i;
        }
    }
    __syncthreads();

    // per-class: insertion sort + greedy NMS (thread c owns class c)
    if (t < NC) {
        int s = start_s[t], e = s + cnt_s[t];
        for (int i = s + 1; i < e; ++i) {
            unsigned long long key = seg[i];
            int j = i - 1;
            while (j >= s && seg[j] > key) { seg[j + 1] = seg[j]; --j; }
            seg[j + 1] = key;
        }
        for (int i = s; i < e; ++i) keep_s[seg[i] & 1023u] = 1;
        for (int i = s; i < e; ++i) {
            int ii = (int)(seg[i] & 1023u);
            if (!keep_s[ii]) continue;
            float4 A = obox_s[ii];
            float aA = area_s[ii];
            for (int j = i + 1; j < e; ++j) {
                int jj = (int)(seg[j] & 1023u);
                if (!keep_s[jj]) continue;
                float4 B = obox_s[jj];
                float ltx = fmaxf(A.x, B.x);
                float lty = fmaxf(A.y, B.y);
                float rbx = fminf(A.z, B.z);
                float rby = fminf(A.w, B.w);
                float w = fmaxf(rbx - ltx, 0.0f);
                float h = fmaxf(rby - lty, 0.0f);
                float inter = w * h;
                float uni = (aA + area_s[jj]) - inter;
                float iou = inter / fmaxf(uni, 1e-9f);   // exact IEEE div
                if (iou > 0.5f) keep_s[jj] = 0;
            }
        }
    }
    __syncthreads();

#pragma unroll
    for (int k = 0; k < 4; ++k) {
        int i = t + k * 256;
        out5[n * G2 + i] = keep_s[i] ? 1.0f : 0.0f;
    }
}

extern "C" void kernel_launch(void* const* d_in, const int* in_sizes, int n_in,
                              void* d_out, int out_size, void* d_ws, size_t ws_size,
                              hipStream_t stream) {
    const float* x = (const float*)d_in[0];
    float* out = (float*)d_out;
    float* out0 = out;                                    // logits  128*1024*80
    float* out1 = out0 + (size_t)NCELL * NC;              // bboxes  128*1024*5
    float* out2 = out1 + (size_t)NCELL * 5;               // boxes   128*1024*4
    float* out3 = out2 + (size_t)NCELL * 4;               // scores  128*1024
    float* out4 = out3 + (size_t)NCELL;                   // reserve 128*1024
    float* out5 = out4 + (size_t)NCELL;                   // keep    128*1024

    int* ws_label = (int*)d_ws;                           // 0.5 MiB

    percell_kernel<<<NCELL / 16, 256, 0, stream>>>(
        x, out0, out1, out2, out3, out4, ws_label);
    nms_kernel<<<NB, 256, 0, stream>>>(
        (const float4*)out2, out3, ws_label, out5);
}